// Round 1
// baseline (1518.412 us; speedup 1.0000x reference)
//
#include <hip/hip_runtime.h>
#include <math.h>

#define NPOS 4096      // H*W
#define DMODEL 256
#define NHEADS 8
#define HDIM 32
#define BATCH 2

// ---------------------------------------------------------------------------
// Kernel 1: neighborhood fuse.  One wave (64 lanes) per position; lane l owns
// float4 dims [4l..4l+3].  10 scores (center + 9 offsets incl. (0,0)) via
// butterfly shfl reduction; softmax in-register; weighted sum.
// ---------------------------------------------------------------------------
__global__ __launch_bounds__(256) void fuse_kernel(const float* __restrict__ x2,
                                                   float* __restrict__ x2f) {
  int wave = threadIdx.x >> 6;
  int lane = threadIdx.x & 63;
  int p = (blockIdx.x << 2) + wave;          // 0..8191
  int b = p >> 12;
  int n = p & 4095;
  int row = n >> 6, col = n & 63;
  const float4* xb = (const float4*)(x2 + (size_t)b * NPOS * DMODEL);
  float4 c4 = xb[(size_t)n * 64 + lane];
  float4 nb[9];
  float sc[10];
  {
    float part = c4.x * c4.x + c4.y * c4.y + c4.z * c4.z + c4.w * c4.w;
    #pragma unroll
    for (int off = 1; off < 64; off <<= 1) part += __shfl_xor(part, off);
    sc[0] = part * 0.0625f;                  // 1/sqrt(256)
  }
  #pragma unroll
  for (int k = 0; k < 9; k++) {
    int di = k / 3 - 1, dj = k % 3 - 1;
    int r = row + di, c = col + dj;
    bool valid = (r >= 0) && (r < 64) && (c >= 0) && (c < 64);
    int nn = valid ? (r * 64 + c) : 0;       // ref gathers idx 0 when invalid
    nb[k] = xb[(size_t)nn * 64 + lane];
    float pp = c4.x * nb[k].x + c4.y * nb[k].y + c4.z * nb[k].z + c4.w * nb[k].w;
    #pragma unroll
    for (int off = 1; off < 64; off <<= 1) pp += __shfl_xor(pp, off);
    sc[k + 1] = valid ? pp * 0.0625f : -3.0e38f;
  }
  float m = sc[0];
  #pragma unroll
  for (int k = 1; k < 10; k++) m = fmaxf(m, sc[k]);
  float w[10], wsum = 0.f;
  #pragma unroll
  for (int k = 0; k < 10; k++) { w[k] = expf(sc[k] - m); wsum += w[k]; }
  float inv = 1.0f / wsum;
  float4 o;
  o.x = c4.x * w[0]; o.y = c4.y * w[0]; o.z = c4.z * w[0]; o.w = c4.w * w[0];
  #pragma unroll
  for (int k = 0; k < 9; k++) {
    o.x += nb[k].x * w[k + 1];
    o.y += nb[k].y * w[k + 1];
    o.z += nb[k].z * w[k + 1];
    o.w += nb[k].w * w[k + 1];
  }
  o.x *= inv; o.y *= inv; o.z *= inv; o.w *= inv;
  ((float4*)(x2f + (size_t)b * NPOS * DMODEL))[(size_t)n * 64 + lane] = o;
}

// ---------------------------------------------------------------------------
// Kernel 2: C[m,j] = sum_d A[m,d]*Wt[j,d] + bias[j]   (A @ W^T + b)
// M=8192, N=256, K=256.  64x64 tile, BK=32, 256 threads, 4x4 micro-tile.
// LDS tiles stored k-major ([32][68] pad: 68%32=4 -> worst 2-way = free).
// SWZ=1 writes [b][head][n][dd] layout for attention; SWZ=0 row-major.
// ---------------------------------------------------------------------------
template <int SWZ>
__global__ __launch_bounds__(256) void proj_gemm(const float* __restrict__ A,
                                                 const float* __restrict__ Wt,
                                                 const float* __restrict__ bias,
                                                 float* __restrict__ C) {
  __shared__ float As_t[32][68];
  __shared__ float Ws_t[32][68];
  int m0 = blockIdx.x * 64;
  int j0 = blockIdx.y * 64;
  int t = threadIdx.x;
  int tx = t & 15, ty = t >> 4;
  float acc[4][4] = {};
  for (int k0 = 0; k0 < 256; k0 += 32) {
    __syncthreads();
    {
      int r = t >> 3;                // 0..31
      int c4 = (t & 7) * 4;          // 0,4,..28
      float4 a0 = *(const float4*)&A[(size_t)(m0 + r) * 256 + k0 + c4];
      float4 a1 = *(const float4*)&A[(size_t)(m0 + r + 32) * 256 + k0 + c4];
      float4 w0 = *(const float4*)&Wt[(size_t)(j0 + r) * 256 + k0 + c4];
      float4 w1 = *(const float4*)&Wt[(size_t)(j0 + r + 32) * 256 + k0 + c4];
      As_t[c4 + 0][r] = a0.x; As_t[c4 + 1][r] = a0.y; As_t[c4 + 2][r] = a0.z; As_t[c4 + 3][r] = a0.w;
      As_t[c4 + 0][r + 32] = a1.x; As_t[c4 + 1][r + 32] = a1.y; As_t[c4 + 2][r + 32] = a1.z; As_t[c4 + 3][r + 32] = a1.w;
      Ws_t[c4 + 0][r] = w0.x; Ws_t[c4 + 1][r] = w0.y; Ws_t[c4 + 2][r] = w0.z; Ws_t[c4 + 3][r] = w0.w;
      Ws_t[c4 + 0][r + 32] = w1.x; Ws_t[c4 + 1][r + 32] = w1.y; Ws_t[c4 + 2][r + 32] = w1.z; Ws_t[c4 + 3][r + 32] = w1.w;
    }
    __syncthreads();
    #pragma unroll
    for (int kk = 0; kk < 32; kk++) {
      float4 a4 = *(const float4*)&As_t[kk][ty * 4];
      float4 b4 = *(const float4*)&Ws_t[kk][tx * 4];
      acc[0][0] += a4.x * b4.x; acc[0][1] += a4.x * b4.y; acc[0][2] += a4.x * b4.z; acc[0][3] += a4.x * b4.w;
      acc[1][0] += a4.y * b4.x; acc[1][1] += a4.y * b4.y; acc[1][2] += a4.y * b4.z; acc[1][3] += a4.y * b4.w;
      acc[2][0] += a4.z * b4.x; acc[2][1] += a4.z * b4.y; acc[2][2] += a4.z * b4.z; acc[2][3] += a4.z * b4.w;
      acc[3][0] += a4.w * b4.x; acc[3][1] += a4.w * b4.y; acc[3][2] += a4.w * b4.z; acc[3][3] += a4.w * b4.w;
    }
  }
  #pragma unroll
  for (int i = 0; i < 4; i++) {
    int m = m0 + ty * 4 + i;
    #pragma unroll
    for (int j = 0; j < 4; j++) {
      int jj = j0 + tx * 4 + j;
      float v = acc[i][j] + bias[jj];
      if (SWZ) {
        int b = m >> 12, n = m & 4095, head = jj >> 5, dd = jj & 31;
        C[(((size_t)(b * NHEADS + head)) * NPOS + n) * HDIM + dd] = v;
      } else {
        C[(size_t)m * 256 + jj] = v;
      }
    }
  }
}

// ---------------------------------------------------------------------------
// Kernel 3: flash attention, fp32.  One thread owns one query row (q,o in
// registers).  Block = 256 threads = 256 queries of one (b,head).  K/V tiles
// (64x32) staged flat in LDS; inner reads are wave-uniform broadcasts.
// Defer-max online softmax (rescale only when max grows by >8).
// ---------------------------------------------------------------------------
__global__ __launch_bounds__(256) void attn_kernel(const float* __restrict__ Q,
                                                   const float* __restrict__ K,
                                                   const float* __restrict__ V,
                                                   float* __restrict__ O) {
  __shared__ float Ks[64 * 32];
  __shared__ float Vs[64 * 32];
  int bh = blockIdx.x >> 4;                 // b*8 + head
  int qt = blockIdx.x & 15;
  const float* Qb = Q + (size_t)bh * NPOS * HDIM;
  const float* Kb = K + (size_t)bh * NPOS * HDIM;
  const float* Vb = V + (size_t)bh * NPOS * HDIM;
  int t = threadIdx.x;
  int n = qt * 256 + t;
  float q[32];
  #pragma unroll
  for (int d4 = 0; d4 < 8; d4++) {
    float4 v4 = *(const float4*)&Qb[(size_t)n * HDIM + d4 * 4];
    q[d4 * 4 + 0] = v4.x; q[d4 * 4 + 1] = v4.y; q[d4 * 4 + 2] = v4.z; q[d4 * 4 + 3] = v4.w;
  }
  float o[32];
  #pragma unroll
  for (int d = 0; d < 32; d++) o[d] = 0.f;
  float mM = -3.0e38f, l = 0.f;
  const float scale = 0.17677669529663687f;  // 1/sqrt(32)

  for (int kt = 0; kt < 64; kt++) {
    __syncthreads();
    {
      const float4* ksrc = (const float4*)(Kb + (size_t)kt * 2048);
      const float4* vsrc = (const float4*)(Vb + (size_t)kt * 2048);
      ((float4*)Ks)[t] = ksrc[t];
      ((float4*)Ks)[t + 256] = ksrc[t + 256];
      ((float4*)Vs)[t] = vsrc[t];
      ((float4*)Vs)[t + 256] = vsrc[t + 256];
    }
    __syncthreads();
    #pragma unroll 2
    for (int j = 0; j < 64; j++) {
      const float4* kr = (const float4*)(Ks + j * 32);
      float s0 = 0.f, s1 = 0.f, s2 = 0.f, s3 = 0.f;
      #pragma unroll
      for (int d4 = 0; d4 < 8; d4 += 4) {
        float4 k0 = kr[d4 + 0], k1 = kr[d4 + 1], k2 = kr[d4 + 2], k3 = kr[d4 + 3];
        s0 += q[d4 * 4 + 0] * k0.x + q[d4 * 4 + 1] * k0.y + q[d4 * 4 + 2] * k0.z + q[d4 * 4 + 3] * k0.w;
        s1 += q[d4 * 4 + 4] * k1.x + q[d4 * 4 + 5] * k1.y + q[d4 * 4 + 6] * k1.z + q[d4 * 4 + 7] * k1.w;
        s2 += q[d4 * 4 + 8] * k2.x + q[d4 * 4 + 9] * k2.y + q[d4 * 4 + 10] * k2.z + q[d4 * 4 + 11] * k2.w;
        s3 += q[d4 * 4 + 12] * k3.x + q[d4 * 4 + 13] * k3.y + q[d4 * 4 + 14] * k3.z + q[d4 * 4 + 15] * k3.w;
      }
      float s = ((s0 + s1) + (s2 + s3)) * scale;
      if (s > mM + 8.0f) {                 // defer-max: rare
        float r = expf(mM - s);
        #pragma unroll
        for (int d = 0; d < 32; d++) o[d] *= r;
        l *= r;
        mM = s;
      }
      float p = expf(s - mM);
      l += p;
      const float4* vr = (const float4*)(Vs + j * 32);
      #pragma unroll
      for (int d4 = 0; d4 < 8; d4++) {
        float4 vv = vr[d4];
        o[d4 * 4 + 0] += p * vv.x;
        o[d4 * 4 + 1] += p * vv.y;
        o[d4 * 4 + 2] += p * vv.z;
        o[d4 * 4 + 3] += p * vv.w;
      }
    }
  }
  float inv = 1.0f / l;
  int b = bh >> 3, head = bh & 7;
  float* Ob = O + ((size_t)(b * NPOS + n)) * DMODEL + head * HDIM;
  #pragma unroll
  for (int d4 = 0; d4 < 8; d4++) {
    float4 v4;
    v4.x = o[d4 * 4 + 0] * inv;
    v4.y = o[d4 * 4 + 1] * inv;
    v4.z = o[d4 * 4 + 2] * inv;
    v4.w = o[d4 * 4 + 3] * inv;
    *(float4*)&Ob[d4 * 4] = v4;
  }
}

// ---------------------------------------------------------------------------
extern "C" void kernel_launch(void* const* d_in, const int* in_sizes, int n_in,
                              void* d_out, int out_size, void* d_ws, size_t ws_size,
                              hipStream_t stream) {
  const float* x1 = (const float*)d_in[0];
  const float* x2 = (const float*)d_in[1];
  const float* Wq = (const float*)d_in[2];
  const float* Wk = (const float*)d_in[3];
  const float* Wv = (const float*)d_in[4];
  const float* Wo = (const float*)d_in[5];
  const float* bq = (const float*)d_in[6];
  const float* bk = (const float*)d_in[7];
  const float* bv = (const float*)d_in[8];
  const float* bo = (const float*)d_in[9];

  float* ws = (float*)d_ws;
  const size_t S = (size_t)BATCH * NPOS * DMODEL;   // 2,097,152 floats
  float* x2f = ws;            // later reused as attn_out (x2f dead by then)
  float* Qb  = ws + S;
  float* Kb  = ws + 2 * S;
  float* Vb  = ws + 3 * S;
  float* out = (float*)d_out;

  fuse_kernel<<<2048, 256, 0, stream>>>(x2, x2f);

  dim3 pg(128, 4);
  proj_gemm<1><<<pg, 256, 0, stream>>>(x1,  Wq, bq, Qb);
  proj_gemm<1><<<pg, 256, 0, stream>>>(x2f, Wk, bk, Kb);
  proj_gemm<1><<<pg, 256, 0, stream>>>(x2f, Wv, bv, Vb);

  attn_kernel<<<256, 256, 0, stream>>>(Qb, Kb, Vb, x2f);  // attn_out -> x2f region

  proj_gemm<0><<<pg, 256, 0, stream>>>(x2f, Wo, bo, out);
}

// Round 4
// 268.142 us; speedup vs baseline: 5.6627x; 5.6627x over previous
//
#include <hip/hip_runtime.h>
#include <hip/hip_bf16.h>
#include <math.h>

#define NPOS 4096      // H*W
#define DMODEL 256
#define NHEADS 8
#define HDIM 32
#define BATCH 2

typedef __bf16 bf16x8 __attribute__((ext_vector_type(8)));
typedef __bf16 bf16x4 __attribute__((ext_vector_type(4)));
typedef float  f32x4  __attribute__((ext_vector_type(4)));

// ---------------------------------------------------------------------------
// Kernel 1: neighborhood fuse (unchanged from passing R1).
// ---------------------------------------------------------------------------
__global__ __launch_bounds__(256) void fuse_kernel(const float* __restrict__ x2,
                                                   float* __restrict__ x2f) {
  int wave = threadIdx.x >> 6;
  int lane = threadIdx.x & 63;
  int p = (blockIdx.x << 2) + wave;          // 0..8191
  int b = p >> 12;
  int n = p & 4095;
  int row = n >> 6, col = n & 63;
  const float4* xb = (const float4*)(x2 + (size_t)b * NPOS * DMODEL);
  float4 c4 = xb[(size_t)n * 64 + lane];
  float4 nb[9];
  float sc[10];
  {
    float part = c4.x * c4.x + c4.y * c4.y + c4.z * c4.z + c4.w * c4.w;
    #pragma unroll
    for (int off = 1; off < 64; off <<= 1) part += __shfl_xor(part, off);
    sc[0] = part * 0.0625f;                  // 1/sqrt(256)
  }
  #pragma unroll
  for (int k = 0; k < 9; k++) {
    int di = k / 3 - 1, dj = k % 3 - 1;
    int r = row + di, c = col + dj;
    bool valid = (r >= 0) && (r < 64) && (c >= 0) && (c < 64);
    int nn = valid ? (r * 64 + c) : 0;
    nb[k] = xb[(size_t)nn * 64 + lane];
    float pp = c4.x * nb[k].x + c4.y * nb[k].y + c4.z * nb[k].z + c4.w * nb[k].w;
    #pragma unroll
    for (int off = 1; off < 64; off <<= 1) pp += __shfl_xor(pp, off);
    sc[k + 1] = valid ? pp * 0.0625f : -3.0e38f;
  }
  float m = sc[0];
  #pragma unroll
  for (int k = 1; k < 10; k++) m = fmaxf(m, sc[k]);
  float w[10], wsum = 0.f;
  #pragma unroll
  for (int k = 0; k < 10; k++) { w[k] = expf(sc[k] - m); wsum += w[k]; }
  float inv = 1.0f / wsum;
  float4 o;
  o.x = c4.x * w[0]; o.y = c4.y * w[0]; o.z = c4.z * w[0]; o.w = c4.w * w[0];
  #pragma unroll
  for (int k = 0; k < 9; k++) {
    o.x += nb[k].x * w[k + 1];
    o.y += nb[k].y * w[k + 1];
    o.z += nb[k].z * w[k + 1];
    o.w += nb[k].w * w[k + 1];
  }
  o.x *= inv; o.y *= inv; o.z *= inv; o.w *= inv;
  ((float4*)(x2f + (size_t)b * NPOS * DMODEL))[(size_t)n * 64 + lane] = o;
}

// ---------------------------------------------------------------------------
// Kernel 2: C = A @ W^T + b.  fp32 math.  MODE 0: fp32 row-major [m][256].
// MODE 1: bf16 [b,h][n][32] (Q/K for attention).  MODE 2: bf16 VT [b,h][32][n].
// ---------------------------------------------------------------------------
template <int MODE>
__global__ __launch_bounds__(256) void proj_gemm(const float* __restrict__ A,
                                                 const float* __restrict__ Wt,
                                                 const float* __restrict__ bias,
                                                 void* __restrict__ Cout) {
  __shared__ float As_t[32][68];
  __shared__ float Ws_t[32][68];
  int m0 = blockIdx.x * 64;
  int j0 = blockIdx.y * 64;
  int t = threadIdx.x;
  int tx = t & 15, ty = t >> 4;
  float acc[4][4] = {};
  for (int k0 = 0; k0 < 256; k0 += 32) {
    __syncthreads();
    {
      int r = t >> 3;
      int c4 = (t & 7) * 4;
      float4 a0 = *(const float4*)&A[(size_t)(m0 + r) * 256 + k0 + c4];
      float4 a1 = *(const float4*)&A[(size_t)(m0 + r + 32) * 256 + k0 + c4];
      float4 w0 = *(const float4*)&Wt[(size_t)(j0 + r) * 256 + k0 + c4];
      float4 w1 = *(const float4*)&Wt[(size_t)(j0 + r + 32) * 256 + k0 + c4];
      As_t[c4 + 0][r] = a0.x; As_t[c4 + 1][r] = a0.y; As_t[c4 + 2][r] = a0.z; As_t[c4 + 3][r] = a0.w;
      As_t[c4 + 0][r + 32] = a1.x; As_t[c4 + 1][r + 32] = a1.y; As_t[c4 + 2][r + 32] = a1.z; As_t[c4 + 3][r + 32] = a1.w;
      Ws_t[c4 + 0][r] = w0.x; Ws_t[c4 + 1][r] = w0.y; Ws_t[c4 + 2][r] = w0.z; Ws_t[c4 + 3][r] = w0.w;
      Ws_t[c4 + 0][r + 32] = w1.x; Ws_t[c4 + 1][r + 32] = w1.y; Ws_t[c4 + 2][r + 32] = w1.z; Ws_t[c4 + 3][r + 32] = w1.w;
    }
    __syncthreads();
    #pragma unroll
    for (int kk = 0; kk < 32; kk++) {
      float4 a4 = *(const float4*)&As_t[kk][ty * 4];
      float4 b4 = *(const float4*)&Ws_t[kk][tx * 4];
      acc[0][0] += a4.x * b4.x; acc[0][1] += a4.x * b4.y; acc[0][2] += a4.x * b4.z; acc[0][3] += a4.x * b4.w;
      acc[1][0] += a4.y * b4.x; acc[1][1] += a4.y * b4.y; acc[1][2] += a4.y * b4.z; acc[1][3] += a4.y * b4.w;
      acc[2][0] += a4.z * b4.x; acc[2][1] += a4.z * b4.y; acc[2][2] += a4.z * b4.z; acc[2][3] += a4.z * b4.w;
      acc[3][0] += a4.w * b4.x; acc[3][1] += a4.w * b4.y; acc[3][2] += a4.w * b4.z; acc[3][3] += a4.w * b4.w;
    }
  }
  if (MODE == 0) {
    float* C = (float*)Cout;
    #pragma unroll
    for (int i = 0; i < 4; i++) {
      int m = m0 + ty * 4 + i;
      #pragma unroll
      for (int j = 0; j < 4; j++) {
        int jj = j0 + tx * 4 + j;
        C[(size_t)m * 256 + jj] = acc[i][j] + bias[jj];
      }
    }
  } else if (MODE == 1) {
    unsigned short* C = (unsigned short*)Cout;
    int jj0 = j0 + tx * 4;
    int head = jj0 >> 5, dd0 = jj0 & 31;
    #pragma unroll
    for (int i = 0; i < 4; i++) {
      int m = m0 + ty * 4 + i;
      int b = m >> 12, n = m & 4095;
      bf16x4 pk;
      #pragma unroll
      for (int j = 0; j < 4; j++) pk[j] = (__bf16)(acc[i][j] + bias[jj0 + j]);
      *(bf16x4*)(C + (((size_t)(b * NHEADS + head) * NPOS + n) * HDIM + dd0)) = pk;
    }
  } else {
    unsigned short* C = (unsigned short*)Cout;
    int m00 = m0 + ty * 4;
    int b = m00 >> 12, n0 = m00 & 4095;
    #pragma unroll
    for (int j = 0; j < 4; j++) {
      int jj = j0 + tx * 4 + j;
      int head = jj >> 5, dd = jj & 31;
      bf16x4 pk;
      #pragma unroll
      for (int i = 0; i < 4; i++) pk[i] = (__bf16)(acc[i][j] + bias[jj]);
      *(bf16x4*)(C + (((size_t)(b * NHEADS + head) * HDIM + dd) * NPOS + n0)) = pk;
    }
  }
}

// ---------------------------------------------------------------------------
// Kernel 3: MFMA flash attention (bf16 in, fp32 accum).
// Wave owns 32 queries.  S^T = K @ Q^T (16x16x32 mfma) so the key axis is
// in-lane: softmax = 16-reg max + 2 shfl_xor.  P -> LDS (XOR swizzle
// k ^= (q&7)<<3, double-buffered, per-wave region, NO __syncthreads) ->
// PV as O^T = V^T @ P^T using pre-transposed VT from global.
// K/VT frags read directly from global: 768 KB/bh, 2 bh per XCD after
// bijective swizzle -> L2-resident (don't stage what L2 fits).
// ---------------------------------------------------------------------------
__global__ __launch_bounds__(256, 2) void attn_mfma(const unsigned short* __restrict__ Qg,
                                                    const unsigned short* __restrict__ Kg,
                                                    const unsigned short* __restrict__ VTg,
                                                    float* __restrict__ O) {
  __shared__ unsigned short Pl[4][2][2048];   // [wave][dbuf][32q x 64k] bf16
  int bid = blockIdx.x;
  int lid = (bid & 7) * 64 + (bid >> 3);      // XCD swizzle (512 = 8*64, bijective)
  int bh = lid >> 5;                          // 16 of them: b*8 + head
  int qblk = (lid & 31) * 128;
  int w = threadIdx.x >> 6;
  int lane = threadIdx.x & 63;
  int q4 = lane & 15, g = lane >> 4;
  int qbase = qblk + w * 32;
  const unsigned short* Qb  = Qg  + (size_t)bh * NPOS * HDIM;
  const unsigned short* Kb  = Kg  + (size_t)bh * NPOS * HDIM;
  const unsigned short* VTb = VTg + (size_t)bh * HDIM * NPOS;

  // Q B-frags (held for whole kernel): lane holds Q[qbase+nf*16+q4][g*8 .. g*8+7]
  bf16x8 qf[2];
  qf[0] = *(const bf16x8*)(Qb + (size_t)(qbase + q4) * HDIM + g * 8);
  qf[1] = *(const bf16x8*)(Qb + (size_t)(qbase + 16 + q4) * HDIM + g * 8);

  f32x4 os[2][2] = {};                        // O^T acc [dm][nf]
  float m2[2] = {-1e30f, -1e30f};
  float lsum[2] = {0.f, 0.f};
  const int swz = (q4 & 7) << 3;
  const float c = 0.17677669529663687f;       // 1/sqrt(32)

  for (int kt = 0; kt < 64; kt++) {
    unsigned short* Pw = Pl[w][kt & 1];
    const unsigned short* Kt = Kb + (size_t)kt * 64 * HDIM;
    // K A-frags: lane holds K[kt*64 + mf*16 + q4][g*8 ..]
    bf16x8 kf[4];
    #pragma unroll
    for (int mf = 0; mf < 4; mf++)
      kf[mf] = *(const bf16x8*)(Kt + (size_t)(mf * 16 + q4) * HDIM + g * 8);
    // VT A-frags: lane holds VT[dm*16 + q4][kt*64 + kk*32 + g*8 ..]
    bf16x8 vf[2][2];
    #pragma unroll
    for (int dm = 0; dm < 2; dm++)
      #pragma unroll
      for (int kk = 0; kk < 2; kk++)
        vf[dm][kk] = *(const bf16x8*)(VTb + (size_t)(dm * 16 + q4) * NPOS + kt * 64 + kk * 32 + g * 8);

    // S^T[k16][q16] = K @ Q^T
    f32x4 s[4][2];
    #pragma unroll
    for (int mf = 0; mf < 4; mf++)
      #pragma unroll
      for (int nf = 0; nf < 2; nf++) {
        f32x4 z = {0.f, 0.f, 0.f, 0.f};
        s[mf][nf] = __builtin_amdgcn_mfma_f32_16x16x32_bf16(kf[mf], qf[nf], z, 0, 0, 0);
      }

    // per-query tile max (16 in-lane regs + 2 shfl across g-groups)
    float tm[2];
    #pragma unroll
    for (int nf = 0; nf < 2; nf++) {
      float a = fmaxf(fmaxf(s[0][nf][0], s[0][nf][1]), fmaxf(s[0][nf][2], s[0][nf][3]));
      #pragma unroll
      for (int mf = 1; mf < 4; mf++) {
        float b2 = fmaxf(fmaxf(s[mf][nf][0], s[mf][nf][1]), fmaxf(s[mf][nf][2], s[mf][nf][3]));
        a = fmaxf(a, b2);
      }
      a = fmaxf(a, __shfl_xor(a, 16));
      a = fmaxf(a, __shfl_xor(a, 32));
      tm[nf] = a * c;                         // scaled domain
    }
    // defer-max (THR=8): rescale only when max grows materially
    float n0 = fmaxf(m2[0], tm[0]), n1 = fmaxf(m2[1], tm[1]);
    if (__any((n0 > m2[0] + 8.f) || (n1 > m2[1] + 8.f))) {
      float r0 = __expf(m2[0] - n0), r1 = __expf(m2[1] - n1);
      lsum[0] *= r0; lsum[1] *= r1;
      os[0][0] *= r0; os[1][0] *= r0;
      os[0][1] *= r1; os[1][1] *= r1;
      m2[0] = n0; m2[1] = n1;
    }

    // P = exp(s*c - m), pack bf16, swizzled LDS write (b64, bank-floor)
    #pragma unroll
    for (int nf = 0; nf < 2; nf++) {
      float mm = m2[nf];
      #pragma unroll
      for (int mf = 0; mf < 4; mf++) {
        bf16x4 pk;
        #pragma unroll
        for (int r = 0; r < 4; r++) {
          float p = __expf(s[mf][nf][r] * c - mm);
          lsum[nf] += p;
          pk[r] = (__bf16)p;
        }
        int k0 = (mf * 16 + g * 4) ^ swz;
        *(bf16x4*)(Pw + (nf * 16 + q4) * 64 + k0) = pk;
      }
    }
    asm volatile("s_waitcnt lgkmcnt(0)" ::: "memory");
    __builtin_amdgcn_sched_barrier(0);

    // PV: O^T[d16][q16] += V^T @ P^T   (B-frag = swizzled b128 reads, bank-floor)
    #pragma unroll
    for (int nf = 0; nf < 2; nf++) {
      bf16x8 pb[2];
      #pragma unroll
      for (int kk = 0; kk < 2; kk++) {
        int k0 = (kk * 32 + g * 8) ^ swz;
        pb[kk] = *(const bf16x8*)(Pw + (nf * 16 + q4) * 64 + k0);
      }
      #pragma unroll
      for (int dm = 0; dm < 2; dm++)
        #pragma unroll
        for (int kk = 0; kk < 2; kk++)
          os[dm][nf] = __builtin_amdgcn_mfma_f32_16x16x32_bf16(vf[dm][kk], pb[kk], os[dm][nf], 0, 0, 0);
    }
  }

  // epilogue: finish l across g-groups, normalize, store fp32 [b][n][256]
  #pragma unroll
  for (int nf = 0; nf < 2; nf++) {
    lsum[nf] += __shfl_xor(lsum[nf], 16);
    lsum[nf] += __shfl_xor(lsum[nf], 32);
  }
  float inv[2] = {1.f / lsum[0], 1.f / lsum[1]};
  int b = bh >> 3, head = bh & 7;
  #pragma unroll
  for (int nf = 0; nf < 2; nf++) {
    int q = qbase + nf * 16 + q4;
    float* Orow = O + ((size_t)(b * NPOS + q)) * DMODEL + head * HDIM;
    #pragma unroll
    for (int dm = 0; dm < 2; dm++) {
      f32x4 v = os[dm][nf] * inv[nf];
      *(f32x4*)(Orow + dm * 16 + g * 4) = v;
    }
  }
}

// ---------------------------------------------------------------------------
extern "C" void kernel_launch(void* const* d_in, const int* in_sizes, int n_in,
                              void* d_out, int out_size, void* d_ws, size_t ws_size,
                              hipStream_t stream) {
  const float* x1 = (const float*)d_in[0];
  const float* x2 = (const float*)d_in[1];
  const float* Wq = (const float*)d_in[2];
  const float* Wk = (const float*)d_in[3];
  const float* Wv = (const float*)d_in[4];
  const float* Wo = (const float*)d_in[5];
  const float* bq = (const float*)d_in[6];
  const float* bk = (const float*)d_in[7];
  const float* bv = (const float*)d_in[8];
  const float* bo = (const float*)d_in[9];

  float* ws = (float*)d_ws;
  const size_t S = (size_t)BATCH * NPOS * DMODEL;      // 2,097,152 floats
  float* x2f  = ws;                                    // 8 MB
  float* attn = ws + S;                                // 8 MB
  unsigned short* ub = (unsigned short*)(ws + 2 * S);
  unsigned short* Qb  = ub;                            // 4 MB bf16
  unsigned short* Kb  = ub + S;                        // 4 MB
  unsigned short* VTb = ub + 2 * S;                    // 4 MB
  float* out = (float*)d_out;

  fuse_kernel<<<2048, 256, 0, stream>>>(x2, x2f);

  dim3 pg(128, 4);
  proj_gemm<1><<<pg, 256, 0, stream>>>(x1,  Wq, bq, (void*)Qb);
  proj_gemm<1><<<pg, 256, 0, stream>>>(x2f, Wk, bk, (void*)Kb);
  proj_gemm<2><<<pg, 256, 0, stream>>>(x2f, Wv, bv, (void*)VTb);

  attn_mfma<<<512, 256, 0, stream>>>(Qb, Kb, VTb, attn);

  proj_gemm<0><<<pg, 256, 0, stream>>>(attn, Wo, bo, (void*)out);
}